// Round 5
// baseline (8438.599 us; speedup 1.0000x reference)
//
#include <hip/hip_runtime.h>

// Problem constants: B=64, T=512, IN=256, H=1024, L=2, OUT=128
#define B_ 64
#define T_ 512
#define IN_ 256
#define H_ 1024
#define OUT_ 128
#define NBLK 64
#define NTHR 512

typedef __attribute__((ext_vector_type(4))) float f32x4;
typedef __attribute__((ext_vector_type(8))) short s16x8;
typedef __attribute__((ext_vector_type(4))) short s16x4;
typedef unsigned short u16;
typedef unsigned long long u64;

// fp32 -> bf16 RNE
__device__ __forceinline__ u16 f2bf(float f) {
  union { float f; unsigned u; } v; v.f = f;
  unsigned r = v.u + 0x7fffu + ((v.u >> 16) & 1u);
  return (u16)(r >> 16);
}
__device__ __forceinline__ float bf2f(u16 h) {
  union { unsigned u; float f; } v; v.u = ((unsigned)h) << 16;
  return v.f;
}
__device__ __forceinline__ s16x8 cvt8(const float* __restrict__ p) {
  float4 a = *(const float4*)p;
  float4 b = *(const float4*)(p + 4);
  s16x8 r;
  r[0] = (short)f2bf(a.x); r[1] = (short)f2bf(a.y);
  r[2] = (short)f2bf(a.z); r[3] = (short)f2bf(a.w);
  r[4] = (short)f2bf(b.x); r[5] = (short)f2bf(b.y);
  r[6] = (short)f2bf(b.z); r[7] = (short)f2bf(b.w);
  return r;
}

// tanh via hardware exp: ~6 VALU ops, error ~1e-6 (<< bf16 quantum).
__device__ __forceinline__ float fast_tanh(float x) {
  float e = __expf(2.0f * x);
  return 1.0f - 2.0f * __builtin_amdgcn_rcpf(e + 1.0f);
}

// Write-through 2B store to the coherence point (MALL): leaves no dirty L2
// line behind -> no writeback fence ever needed. (Validated round 4.)
__device__ __forceinline__ void store_wt_u16(u16* p, u16 v) {
  unsigned d = v;
  asm volatile("global_store_short %0, %1, off sc0 sc1" :: "v"(p), "v"(d) : "memory");
}

// Coherent 16B load from MALL (bypasses L1/L2, allocates nothing -> no stale
// copies can form). Used ONLY for the h1 ping-pong buffers, whose addresses
// are rewritten within a dispatch.
__device__ __forceinline__ s16x8 load_coh16(const u16* p) {
  const u64* q = (const u64*)p;
  union { u64 qq[2]; s16x8 v; } u;
  u.qq[0] = __hip_atomic_load(q + 0, __ATOMIC_RELAXED, __HIP_MEMORY_SCOPE_AGENT);
  u.qq[1] = __hip_atomic_load(q + 1, __ATOMIC_RELAXED, __HIP_MEMORY_SCOPE_AGENT);
  return u.v;
}

// Fence-free grid barrier, monotonic-counter protocol:
//   release = s_waitcnt vmcnt(0) (caller) on write-through stores
//   arrival = relaxed agent fetch_add on a monotonically growing counter
//   winner  = arrival count hits gen*NBLK -> relaxed store of generation flag
//   losers  = poll generation flag (agent-scope loads go to MALL)
// No reset (monotonic) -> no reset/bump ordering hazard. No buffer_inv,
// no buffer_wbl2, ever. Counter at bar[0], gen flag at bar[32] (128B apart).
__device__ __forceinline__ void grid_barrier_nf(unsigned* bar, unsigned gen) {
  __syncthreads();
  if (threadIdx.x == 0) {
    unsigned arrived =
        __hip_atomic_fetch_add(bar, 1u, __ATOMIC_RELAXED, __HIP_MEMORY_SCOPE_AGENT) + 1u;
    if (arrived == gen * NBLK) {
      __hip_atomic_store(bar + 32, gen, __ATOMIC_RELAXED, __HIP_MEMORY_SCOPE_AGENT);
    } else {
      while (__hip_atomic_load(bar + 32, __ATOMIC_RELAXED, __HIP_MEMORY_SCOPE_AGENT) < gen) {
        __builtin_amdgcn_s_sleep(1);
      }
    }
  }
  __syncthreads();
}

// ---------------------------------------------------------------------------
// x [B][T][IN] fp32 -> xbf [T*B][IN] bf16 (step-major rows)
// ---------------------------------------------------------------------------
__global__ __launch_bounds__(256) void cvt_x(const float* __restrict__ x,
                                             u16* __restrict__ xbf) {
  int i4 = blockIdx.x * 256 + threadIdx.x;
  int r = i4 >> 6;
  int kc = (i4 & 63) * 4;
  int t = r >> 6, b = r & 63;
  float4 v = *(const float4*)(x + ((size_t)b * T_ + t) * IN_ + kc);
  s16x4 o;
  o[0] = (short)f2bf(v.x); o[1] = (short)f2bf(v.y);
  o[2] = (short)f2bf(v.z); o[3] = (short)f2bf(v.w);
  *(s16x4*)(xbf + (size_t)r * IN_ + kc) = o;
}

__global__ __launch_bounds__(256) void cvt_w(const float* __restrict__ w,
                                             u16* __restrict__ wbf) {
  int i = blockIdx.x * 256 + threadIdx.x;
  float4 v = *(const float4*)(w + (size_t)i * 4);
  s16x4 o;
  o[0] = (short)f2bf(v.x); o[1] = (short)f2bf(v.y);
  o[2] = (short)f2bf(v.z); o[3] = (short)f2bf(v.w);
  *(s16x4*)(wbf + (size_t)i * 4) = o;
}

// ---------------------------------------------------------------------------
// xw0[r=t*64+b][j] = x_row[r] @ W_ih0^T + (b_ih0 + b_hh0), stored bf16.
// (unchanged — validated rounds 3/4)
// ---------------------------------------------------------------------------
__global__ __launch_bounds__(256) void xw0_mfma(const u16* __restrict__ xbf,
                                                const u16* __restrict__ w0bf,
                                                const float* __restrict__ bih,
                                                const float* __restrict__ bhh,
                                                u16* __restrict__ xw0) {
  __shared__ char ldsW[64 * 512];
  const int tid = threadIdx.x;
  const int j0 = blockIdx.x * 64;
  const int r0 = blockIdx.y * 64;

  for (int c = tid; c < 64 * 32; c += 256) {
    int r = c >> 5, kc = c & 31;
    s16x8 w = *(const s16x8*)(w0bf + (size_t)(j0 + r) * IN_ + kc * 8);
    *(s16x8*)(ldsW + r * 512 + ((kc * 16) ^ ((r & 7) << 4))) = w;
  }
  __syncthreads();

  const int wv = tid >> 6, lane = tid & 63;
  const int col = lane & 15, kg = lane >> 4;
  const int rr = r0 + wv * 16 + col;
  const u16* aRow = xbf + (size_t)rr * IN_ + kg * 8;

  f32x4 acc[4] = {};
#pragma unroll
  for (int k0 = 0; k0 < IN_; k0 += 32) {
    s16x8 a = *(const s16x8*)(aRow + k0);
#pragma unroll
    for (int n = 0; n < 4; ++n) {
      int jr = n * 16 + col;
      s16x8 b = *(const s16x8*)(ldsW + jr * 512 + ((((k0 + kg * 8) << 1)) ^ ((jr & 7) << 4)));
      acc[n] = __builtin_amdgcn_mfma_f32_16x16x32_bf16(a, b, acc[n], 0, 0, 0);
    }
  }
#pragma unroll
  for (int n = 0; n < 4; ++n) {
    int j = j0 + n * 16 + col;
    float bs = bih[j] + bhh[j];
#pragma unroll
    for (int q = 0; q < 4; ++q) {
      int r = r0 + wv * 16 + kg * 4 + q;
      xw0[(size_t)r * H_ + j] = f2bf(acc[n][q] + bs);
    }
  }
}

// ---------------------------------------------------------------------------
// Persistent cooperative kernel. 64 blocks x 512 threads (8 waves).
// Block jg owns 16 j-cols of both layers; waves 0-3 = layer 0, 4-7 = layer 1,
// pipelined one step apart. One fence-free barrier per step.
// Staleness audit: ys0[t]/xw0[t] = write-once fresh addresses -> normal loads;
// h1a/h1b = reused addresses -> coherent (MALL) loads only.
// ---------------------------------------------------------------------------
__global__ __launch_bounds__(NTHR, 1) void rnn_seq(
    const float* __restrict__ Whh0, const float* __restrict__ Wih1,
    const float* __restrict__ Whh1, const float* __restrict__ bih1,
    const float* __restrict__ bhh1, const float* __restrict__ Wlin,
    const float* __restrict__ blin, const u16* __restrict__ xw0bf,
    u16* __restrict__ ys0, u16* __restrict__ h1a, u16* __restrict__ h1b,
    unsigned* __restrict__ bar, float* __restrict__ out) {
  extern __shared__ char lds[];
  char* ldsW0 = lds;           // 16 rows x 2048 B
  char* ldsW1 = lds + 32768;   // 16 rows x 4096 B
  const int tid = threadIdx.x;
  const int blk = blockIdx.x;  // jg 0..63
  const int j0 = blk * 16;
  const int wv = tid >> 6, lane = tid & 63;
  const int col = lane & 15, kg = lane >> 4;
  const int sw = (col & 7) << 4;
  const int b0 = (wv & 3) * 16;
  const bool isL1 = wv >= 4;

  // stage W0 slice (16 x 1024 bf16), fp32->bf16, swizzled
  for (int c = tid; c < 16 * 128; c += NTHR) {
    int r = c >> 7, kc = c & 127;
    s16x8 w = cvt8(Whh0 + (size_t)(j0 + r) * H_ + kc * 8);
    *(s16x8*)(ldsW0 + r * 2048 + ((kc * 16) ^ ((r & 7) << 4))) = w;
  }
  // stage W1 slice (16 x 2048 bf16): [0,1024)=Wih1, [1024,2048)=Whh1
  for (int c = tid; c < 16 * 256; c += NTHR) {
    int r = c >> 8, kc = c & 255;
    const float* src = (kc < 128) ? (Wih1 + (size_t)(j0 + r) * H_ + kc * 8)
                                  : (Whh1 + (size_t)(j0 + r) * H_ + (kc - 128) * 8);
    *(s16x8*)(ldsW1 + r * 4096 + ((kc * 16) ^ ((r & 7) << 4))) = cvt8(src);
  }
  __syncthreads();

  const float bias1 = bih1[j0 + col] + bhh1[j0 + col];

  for (int s = 0; s <= T_; ++s) {
    if (!isL1) {
      if (s < T_) {
        const u16* xwp =
            xw0bf + (size_t)s * (B_ * H_) + (size_t)(b0 + kg * 4) * H_ + j0 + col;
        u16 xv0 = xwp[0], xv1 = xwp[H_], xv2 = xwp[2 * H_], xv3 = xwp[3 * H_];
        f32x4 acc0 = {}, acc1 = {};
        if (s > 0) {
          const u16* aRow =
              ys0 + (size_t)(s - 1) * (B_ * H_) + (size_t)(b0 + col) * H_ + kg * 8;
          const char* bB = ldsW0 + col * 2048;
#pragma unroll
          for (int k0 = 0; k0 < H_; k0 += 64) {
            s16x8 a0 = *(const s16x8*)(aRow + k0);
            s16x8 w0 = *(const s16x8*)(bB + (((k0 + kg * 8) << 1) ^ sw));
            acc0 = __builtin_amdgcn_mfma_f32_16x16x32_bf16(a0, w0, acc0, 0, 0, 0);
            s16x8 a1 = *(const s16x8*)(aRow + k0 + 32);
            s16x8 w1 = *(const s16x8*)(bB + (((k0 + 32 + kg * 8) << 1) ^ sw));
            acc1 = __builtin_amdgcn_mfma_f32_16x16x32_bf16(a1, w1, acc1, 0, 0, 0);
          }
        }
        f32x4 acc = acc0 + acc1;
        u16* ysC = ys0 + (size_t)s * (B_ * H_) + (size_t)(b0 + kg * 4) * H_ + j0 + col;
        store_wt_u16(ysC + 0 * H_, f2bf(fast_tanh(acc[0] + bf2f(xv0))));
        store_wt_u16(ysC + 1 * H_, f2bf(fast_tanh(acc[1] + bf2f(xv1))));
        store_wt_u16(ysC + 2 * H_, f2bf(fast_tanh(acc[2] + bf2f(xv2))));
        store_wt_u16(ysC + 3 * H_, f2bf(fast_tanh(acc[3] + bf2f(xv3))));
      }
    } else {
      if (s >= 1) {
        const int t1 = s - 1;
        u16* h1c = (t1 & 1) ? h1b : h1a;
        const u16* h1p = (t1 & 1) ? h1a : h1b;
        f32x4 acc0 = {}, acc1 = {};
        const char* bB = ldsW1 + col * 4096;
        const u16* a1 =
            ys0 + (size_t)t1 * (B_ * H_) + (size_t)(b0 + col) * H_ + kg * 8;
#pragma unroll
        for (int k0 = 0; k0 < H_; k0 += 64) {
          s16x8 a0 = *(const s16x8*)(a1 + k0);
          s16x8 w0 = *(const s16x8*)(bB + (((k0 + kg * 8) << 1) ^ sw));
          acc0 = __builtin_amdgcn_mfma_f32_16x16x32_bf16(a0, w0, acc0, 0, 0, 0);
          s16x8 a1v = *(const s16x8*)(a1 + k0 + 32);
          s16x8 w1 = *(const s16x8*)(bB + (((k0 + 32 + kg * 8) << 1) ^ sw));
          acc1 = __builtin_amdgcn_mfma_f32_16x16x32_bf16(a1v, w1, acc1, 0, 0, 0);
        }
        if (t1 > 0) {
          const u16* a2 = h1p + (size_t)(b0 + col) * H_ + kg * 8;
#pragma unroll
          for (int k0 = 0; k0 < H_; k0 += 64) {
            s16x8 a0 = load_coh16(a2 + k0);
            s16x8 w0 = *(const s16x8*)(bB + ((2048 + ((k0 + kg * 8) << 1)) ^ sw));
            acc0 = __builtin_amdgcn_mfma_f32_16x16x32_bf16(a0, w0, acc0, 0, 0, 0);
            s16x8 a1v = load_coh16(a2 + k0 + 32);
            s16x8 w1 = *(const s16x8*)(bB + ((2048 + ((k0 + 32 + kg * 8) << 1)) ^ sw));
            acc1 = __builtin_amdgcn_mfma_f32_16x16x32_bf16(a1v, w1, acc1, 0, 0, 0);
          }
        }
        f32x4 acc = acc0 + acc1;
        u16* hc = h1c + (size_t)(b0 + kg * 4) * H_ + j0 + col;
        store_wt_u16(hc + 0 * H_, f2bf(fast_tanh(acc[0] + bias1)));
        store_wt_u16(hc + 1 * H_, f2bf(fast_tanh(acc[1] + bias1)));
        store_wt_u16(hc + 2 * H_, f2bf(fast_tanh(acc[2] + bias1)));
        store_wt_u16(hc + 3 * H_, f2bf(fast_tanh(acc[3] + bias1)));
      }
    }
    // release: drain write-through stores to the coherence point
    asm volatile("s_waitcnt vmcnt(0)" ::: "memory");
    grid_barrier_nf(bar, (unsigned)(s + 1));
  }

  // ---- final linear + sigmoid: out[64][128], block b = blk, thread o = tid
  if (tid < OUT_) {
    const int o = tid;
    const u16* hA = ys0 + (size_t)(T_ - 1) * (B_ * H_) + (size_t)blk * H_;
    const u16* hB = h1b + (size_t)blk * H_;  // t=511 odd -> h1b
    const float* wr = Wlin + (size_t)o * (2 * H_);
    float acc = blin[o];
#pragma unroll 4
    for (int k = 0; k < H_; k += 8) {
      s16x8 h = *(const s16x8*)(hA + k);
      float4 w0 = *(const float4*)(wr + k);
      float4 w1 = *(const float4*)(wr + k + 4);
      acc += bf2f((u16)h[0]) * w0.x + bf2f((u16)h[1]) * w0.y +
             bf2f((u16)h[2]) * w0.z + bf2f((u16)h[3]) * w0.w +
             bf2f((u16)h[4]) * w1.x + bf2f((u16)h[5]) * w1.y +
             bf2f((u16)h[6]) * w1.z + bf2f((u16)h[7]) * w1.w;
    }
#pragma unroll 4
    for (int k = 0; k < H_; k += 8) {
      s16x8 h = load_coh16(hB + k);  // h1b is a reused address: MALL read
      float4 w0 = *(const float4*)(wr + H_ + k);
      float4 w1 = *(const float4*)(wr + H_ + k + 4);
      acc += bf2f((u16)h[0]) * w0.x + bf2f((u16)h[1]) * w0.y +
             bf2f((u16)h[2]) * w0.z + bf2f((u16)h[3]) * w0.w +
             bf2f((u16)h[4]) * w1.x + bf2f((u16)h[5]) * w1.y +
             bf2f((u16)h[6]) * w1.z + bf2f((u16)h[7]) * w1.w;
    }
    out[blk * OUT_ + o] = 1.0f / (1.0f + expf(-acc));
  }
}

// ---------------------------------------------------------------------------
extern "C" void kernel_launch(void* const* d_in, const int* in_sizes, int n_in,
                              void* d_out, int out_size, void* d_ws, size_t ws_size,
                              hipStream_t stream) {
  const float* x    = (const float*)d_in[0];
  const float* Wih0 = (const float*)d_in[1];
  const float* Whh0 = (const float*)d_in[2];
  const float* bih0 = (const float*)d_in[3];
  const float* bhh0 = (const float*)d_in[4];
  const float* Wih1 = (const float*)d_in[5];
  const float* Whh1 = (const float*)d_in[6];
  const float* bih1 = (const float*)d_in[7];
  const float* bhh1 = (const float*)d_in[8];
  const float* Wlin = (const float*)d_in[9];
  const float* blin = (const float*)d_in[10];
  float* out = (float*)d_out;

  char* ws = (char*)d_ws;
  const size_t TBH = (size_t)T_ * B_ * H_;
  u16* xw0bf = (u16*)ws;                    // 64 MB
  u16* ys0   = (u16*)(ws + TBH * 2);        // 64 MB
  u16* xbf  = ys0;                          // aliases (dead before rnn_seq)
  u16* w0bf = ys0 + (size_t)T_ * B_ * IN_;
  u16* h1a  = (u16*)(ws + 2 * TBH * 2);
  u16* h1b  = h1a + B_ * H_;
  unsigned* bar = (unsigned*)(h1b + B_ * H_);

  hipMemsetAsync(bar, 0, 256, stream);

  cvt_x<<<8192, 256, 0, stream>>>(x, xbf);
  cvt_w<<<256, 256, 0, stream>>>(Wih0, w0bf);
  xw0_mfma<<<dim3(16, 512), 256, 0, stream>>>(xbf, w0bf, bih0, bhh0, xw0bf);

  const int dyn_lds = 98304;  // 32KB W0 + 64KB W1
  hipFuncSetAttribute((const void*)rnn_seq, hipFuncAttributeMaxDynamicSharedMemorySize,
                      dyn_lds);
  void* args[] = {&Whh0, &Wih1, &Whh1, &bih1, &bhh1, &Wlin, &blin,
                  &xw0bf, &ys0, &h1a, &h1b, &bar, &out};
  hipLaunchCooperativeKernel((const void*)rnn_seq, dim3(NBLK), dim3(NTHR), args, dyn_lds,
                             stream);
}

// Round 6
// 6424.893 us; speedup vs baseline: 1.3134x; 1.3134x over previous
//
#include <hip/hip_runtime.h>

// Problem constants: B=64, T=512, IN=256, H=1024, L=2, OUT=128
#define B_ 64
#define T_ 512
#define IN_ 256
#define H_ 1024
#define OUT_ 128
#define NBLK 64
#define NTHR 512

typedef __attribute__((ext_vector_type(4))) float f32x4;
typedef __attribute__((ext_vector_type(8))) short s16x8;
typedef __attribute__((ext_vector_type(4))) short s16x4;
typedef unsigned short u16;
typedef unsigned long long u64;

// fp32 -> bf16 RNE
__device__ __forceinline__ u16 f2bf(float f) {
  union { float f; unsigned u; } v; v.f = f;
  unsigned r = v.u + 0x7fffu + ((v.u >> 16) & 1u);
  return (u16)(r >> 16);
}
__device__ __forceinline__ float bf2f(u16 h) {
  union { unsigned u; float f; } v; v.u = ((unsigned)h) << 16;
  return v.f;
}
__device__ __forceinline__ s16x8 cvt8(const float* __restrict__ p) {
  float4 a = *(const float4*)p;
  float4 b = *(const float4*)(p + 4);
  s16x8 r;
  r[0] = (short)f2bf(a.x); r[1] = (short)f2bf(a.y);
  r[2] = (short)f2bf(a.z); r[3] = (short)f2bf(a.w);
  r[4] = (short)f2bf(b.x); r[5] = (short)f2bf(b.y);
  r[6] = (short)f2bf(b.z); r[7] = (short)f2bf(b.w);
  return r;
}

// tanh via hardware exp (validated round 5: absmax unchanged vs tanhf).
__device__ __forceinline__ float fast_tanh(float x) {
  float e = __expf(2.0f * x);
  return 1.0f - 2.0f * __builtin_amdgcn_rcpf(e + 1.0f);
}

// Write-through 2B store to the coherence point (validated rounds 4/5).
__device__ __forceinline__ void store_wt_u16(u16* p, u16 v) {
  unsigned d = v;
  asm volatile("global_store_short %0, %1, off sc0 sc1" :: "v"(p), "v"(d) : "memory");
}

// Coherent 16B load (MALL, no L1/L2 allocation) for reused-address buffers.
__device__ __forceinline__ s16x8 load_coh16(const u16* p) {
  const u64* q = (const u64*)p;
  union { u64 qq[2]; s16x8 v; } u;
  u.qq[0] = __hip_atomic_load(q + 0, __ATOMIC_RELAXED, __HIP_MEMORY_SCOPE_AGENT);
  u.qq[1] = __hip_atomic_load(q + 1, __ATOMIC_RELAXED, __HIP_MEMORY_SCOPE_AGENT);
  return u.v;
}

// ---------------------------------------------------------------------------
// x [B][T][IN] fp32 -> xbf [T*B][IN] bf16 (step-major rows)
// ---------------------------------------------------------------------------
__global__ __launch_bounds__(256) void cvt_x(const float* __restrict__ x,
                                             u16* __restrict__ xbf) {
  int i4 = blockIdx.x * 256 + threadIdx.x;
  int r = i4 >> 6;
  int kc = (i4 & 63) * 4;
  int t = r >> 6, b = r & 63;
  float4 v = *(const float4*)(x + ((size_t)b * T_ + t) * IN_ + kc);
  s16x4 o;
  o[0] = (short)f2bf(v.x); o[1] = (short)f2bf(v.y);
  o[2] = (short)f2bf(v.z); o[3] = (short)f2bf(v.w);
  *(s16x4*)(xbf + (size_t)r * IN_ + kc) = o;
}

__global__ __launch_bounds__(256) void cvt_w(const float* __restrict__ w,
                                             u16* __restrict__ wbf) {
  int i = blockIdx.x * 256 + threadIdx.x;
  float4 v = *(const float4*)(w + (size_t)i * 4);
  s16x4 o;
  o[0] = (short)f2bf(v.x); o[1] = (short)f2bf(v.y);
  o[2] = (short)f2bf(v.z); o[3] = (short)f2bf(v.w);
  *(s16x4*)(wbf + (size_t)i * 4) = o;
}

// ---------------------------------------------------------------------------
// xw0 precompute (unchanged — validated rounds 3-5)
// ---------------------------------------------------------------------------
__global__ __launch_bounds__(256) void xw0_mfma(const u16* __restrict__ xbf,
                                                const u16* __restrict__ w0bf,
                                                const float* __restrict__ bih,
                                                const float* __restrict__ bhh,
                                                u16* __restrict__ xw0) {
  __shared__ char ldsW[64 * 512];
  const int tid = threadIdx.x;
  const int j0 = blockIdx.x * 64;
  const int r0 = blockIdx.y * 64;

  for (int c = tid; c < 64 * 32; c += 256) {
    int r = c >> 5, kc = c & 31;
    s16x8 w = *(const s16x8*)(w0bf + (size_t)(j0 + r) * IN_ + kc * 8);
    *(s16x8*)(ldsW + r * 512 + ((kc * 16) ^ ((r & 7) << 4))) = w;
  }
  __syncthreads();

  const int wv = tid >> 6, lane = tid & 63;
  const int col = lane & 15, kg = lane >> 4;
  const int rr = r0 + wv * 16 + col;
  const u16* aRow = xbf + (size_t)rr * IN_ + kg * 8;

  f32x4 acc[4] = {};
#pragma unroll
  for (int k0 = 0; k0 < IN_; k0 += 32) {
    s16x8 a = *(const s16x8*)(aRow + k0);
#pragma unroll
    for (int n = 0; n < 4; ++n) {
      int jr = n * 16 + col;
      s16x8 b = *(const s16x8*)(ldsW + jr * 512 + ((((k0 + kg * 8) << 1)) ^ ((jr & 7) << 4)));
      acc[n] = __builtin_amdgcn_mfma_f32_16x16x32_bf16(a, b, acc[n], 0, 0, 0);
    }
  }
#pragma unroll
  for (int n = 0; n < 4; ++n) {
    int j = j0 + n * 16 + col;
    float bs = bih[j] + bhh[j];
#pragma unroll
    for (int q = 0; q < 4; ++q) {
      int r = r0 + wv * 16 + kg * 4 + q;
      xw0[(size_t)r * H_ + j] = f2bf(acc[n][q] + bs);
    }
  }
}

// ---------------------------------------------------------------------------
// Persistent cooperative kernel. 64 blocks x 512 threads (8 waves).
// Block jg owns 16 j-cols. Per step s:
//   L0 waves 0-3 (b-tile wv*16): load ys[s-1] rows once; compute BOTH
//     P_ih = ys[s-1] @ Wih1^T  (-> 4KB LDS, for the L1 waves)   and
//     ys[s] = tanh(xw0[s] + ys[s-1] @ Whh0^T)                   (WT store)
//   L1 waves 4-7 (b-tile (wv-4)*16): h-part = h1[t1-1] @ Whh1^T via
//     16B MALL-bypass loads; after __syncthreads, add P_ih + bias, tanh,
//     WT store h1[t1], t1 = s-1.
// Barrier: per-block WT flag store (after vmcnt(0) drain) + wave0 polls all
// 64 flags with one 64-lane sc0sc1 load. No atomics, no fences, no winner.
// ---------------------------------------------------------------------------
__global__ __launch_bounds__(NTHR, 1) void rnn_seq(
    const float* __restrict__ Whh0, const float* __restrict__ Wih1,
    const float* __restrict__ Whh1, const float* __restrict__ bih1,
    const float* __restrict__ bhh1, const float* __restrict__ Wlin,
    const float* __restrict__ blin, const u16* __restrict__ xw0bf,
    u16* __restrict__ ys0, u16* __restrict__ h1a, u16* __restrict__ h1b,
    unsigned* __restrict__ flags, float* __restrict__ out) {
  extern __shared__ char lds[];
  char* ldsW0 = lds;                      // 16 x 2048 B
  char* ldsW1 = lds + 32768;              // 16 x 4096 B
  float* ldsP = (float*)(lds + 98304);    // 4 tiles x 16 x 16 f32 = 4 KB
  const int tid = threadIdx.x;
  const int blk = blockIdx.x;             // jg 0..63
  const int j0 = blk * 16;
  const int wv = tid >> 6, lane = tid & 63;
  const int col = lane & 15, kg = lane >> 4;
  const int sw = (col & 7) << 4;
  const int bt = wv & 3;
  const int b0 = bt * 16;
  const bool isL1 = wv >= 4;

  // stage W0 slice (16 x 1024 bf16), fp32->bf16, swizzled
  for (int c = tid; c < 16 * 128; c += NTHR) {
    int r = c >> 7, kc = c & 127;
    s16x8 w = cvt8(Whh0 + (size_t)(j0 + r) * H_ + kc * 8);
    *(s16x8*)(ldsW0 + r * 2048 + ((kc * 16) ^ ((r & 7) << 4))) = w;
  }
  // stage W1 slice (16 x 2048 bf16): [0,1024)=Wih1, [1024,2048)=Whh1
  for (int c = tid; c < 16 * 256; c += NTHR) {
    int r = c >> 8, kc = c & 255;
    const float* src = (kc < 128) ? (Wih1 + (size_t)(j0 + r) * H_ + kc * 8)
                                  : (Whh1 + (size_t)(j0 + r) * H_ + (kc - 128) * 8);
    *(s16x8*)(ldsW1 + r * 4096 + ((kc * 16) ^ ((r & 7) << 4))) = cvt8(src);
  }
  __syncthreads();

  const float bias1 = bih1[j0 + col] + bhh1[j0 + col];

  // prologue: xw0[0] additive tile
  u16 xv0 = 0, xv1 = 0, xv2 = 0, xv3 = 0;
  if (!isL1) {
    const u16* xwp = xw0bf + (size_t)(b0 + kg * 4) * H_ + j0 + col;
    xv0 = xwp[0]; xv1 = xwp[H_]; xv2 = xwp[2 * H_]; xv3 = xwp[3 * H_];
  }

  for (int s = 0; s <= T_; ++s) {
    const unsigned gen = (unsigned)(s + 1);
    f32x4 accH0 = {}, accH1 = {};

    if (!isL1) {
      // ---------------- layer-0 waves: P_ih partial + ys[s] ----------------
      f32x4 accY0 = {}, accY1 = {};
      if (s > 0) {
        const u16* aRow =
            ys0 + (size_t)(s - 1) * (B_ * H_) + (size_t)(b0 + col) * H_ + kg * 8;
        s16x8 af[32];
#pragma unroll
        for (int i = 0; i < 32; ++i) af[i] = *(const s16x8*)(aRow + i * 32);
        const char* w0B = ldsW0 + col * 2048;
        const char* w1B = ldsW1 + col * 4096;
        f32x4 accP0 = {}, accP1 = {};
#pragma unroll
        for (int i = 0; i < 32; ++i) {
          const int kb = ((i * 32 + kg * 8) << 1);
          s16x8 wP = *(const s16x8*)(w1B + (kb ^ sw));
          s16x8 wY = *(const s16x8*)(w0B + (kb ^ sw));
          if (i & 1) {
            accP1 = __builtin_amdgcn_mfma_f32_16x16x32_bf16(af[i], wP, accP1, 0, 0, 0);
            accY1 = __builtin_amdgcn_mfma_f32_16x16x32_bf16(af[i], wY, accY1, 0, 0, 0);
          } else {
            accP0 = __builtin_amdgcn_mfma_f32_16x16x32_bf16(af[i], wP, accP0, 0, 0, 0);
            accY0 = __builtin_amdgcn_mfma_f32_16x16x32_bf16(af[i], wY, accY0, 0, 0, 0);
          }
        }
        f32x4 accP = accP0 + accP1;
        float* pT = ldsP + bt * 256 + (kg * 4) * 16 + col;
        pT[0] = accP[0]; pT[16] = accP[1]; pT[32] = accP[2]; pT[48] = accP[3];
      }
      if (s < T_) {
        f32x4 accY = accY0 + accY1;
        u16* ysC = ys0 + (size_t)s * (B_ * H_) + (size_t)(b0 + kg * 4) * H_ + j0 + col;
        store_wt_u16(ysC + 0 * H_, f2bf(fast_tanh(accY[0] + bf2f(xv0))));
        store_wt_u16(ysC + 1 * H_, f2bf(fast_tanh(accY[1] + bf2f(xv1))));
        store_wt_u16(ysC + 2 * H_, f2bf(fast_tanh(accY[2] + bf2f(xv2))));
        store_wt_u16(ysC + 3 * H_, f2bf(fast_tanh(accY[3] + bf2f(xv3))));
      }
      asm volatile("s_waitcnt vmcnt(0)" ::: "memory");
    } else {
      // ---------------- layer-1 waves: h-part only ----------------
      if (s >= 2) {
        const int t1 = s - 1;
        const u16* h1p = (t1 & 1) ? h1a : h1b;
        const u16* hRow = h1p + (size_t)(b0 + col) * H_ + kg * 8;
        s16x8 hf[32];
#pragma unroll
        for (int i = 0; i < 32; ++i)
          asm volatile("global_load_dwordx4 %0, %1, off sc0 sc1"
                       : "=v"(hf[i]) : "v"(hRow + i * 32) : "memory");
        const char* w1B = ldsW1 + col * 4096;
        asm volatile("s_waitcnt vmcnt(16)" ::: "memory");
        __builtin_amdgcn_sched_barrier(0);
#pragma unroll
        for (int i = 0; i < 16; ++i) {
          const int kb = 2048 + ((i * 32 + kg * 8) << 1);
          s16x8 w = *(const s16x8*)(w1B + (kb ^ sw));
          accH0 = __builtin_amdgcn_mfma_f32_16x16x32_bf16(hf[i], w, accH0, 0, 0, 0);
        }
        asm volatile("s_waitcnt vmcnt(0)" ::: "memory");
        __builtin_amdgcn_sched_barrier(0);
#pragma unroll
        for (int i = 16; i < 32; ++i) {
          const int kb = 2048 + ((i * 32 + kg * 8) << 1);
          s16x8 w = *(const s16x8*)(w1B + (kb ^ sw));
          accH1 = __builtin_amdgcn_mfma_f32_16x16x32_bf16(hf[i], w, accH1, 0, 0, 0);
        }
      }
    }

    __syncthreads();  // #1 — P_ih visible to L1 waves

    if (isL1 && s >= 1) {
      const int t1 = s - 1;
      f32x4 acc = accH0 + accH1;
      const float* pT = ldsP + bt * 256 + (kg * 4) * 16 + col;
      acc[0] += pT[0]; acc[1] += pT[16]; acc[2] += pT[32]; acc[3] += pT[48];
      u16* hc = ((t1 & 1) ? h1b : h1a) + (size_t)(b0 + kg * 4) * H_ + j0 + col;
      store_wt_u16(hc + 0 * H_, f2bf(fast_tanh(acc[0] + bias1)));
      store_wt_u16(hc + 1 * H_, f2bf(fast_tanh(acc[1] + bias1)));
      store_wt_u16(hc + 2 * H_, f2bf(fast_tanh(acc[2] + bias1)));
      store_wt_u16(hc + 3 * H_, f2bf(fast_tanh(acc[3] + bias1)));
      asm volatile("s_waitcnt vmcnt(0)" ::: "memory");
    }

    __syncthreads();  // #2 — all block stores drained to MALL

    if (tid == 0) {
      asm volatile("global_store_dword %0, %1, off sc0 sc1"
                   :: "v"(flags + blk), "v"(gen) : "memory");
    }
    // prefetch next step's xw0 tile during the wait (precomputed data)
    if (!isL1 && s + 1 < T_) {
      const u16* xwp =
          xw0bf + (size_t)(s + 1) * (B_ * H_) + (size_t)(b0 + kg * 4) * H_ + j0 + col;
      xv0 = xwp[0]; xv1 = xwp[H_]; xv2 = xwp[2 * H_]; xv3 = xwp[3 * H_];
    }
    if (tid < 64) {
      unsigned v;
      do {
        asm volatile("global_load_dword %0, %1, off sc0 sc1\n\ts_waitcnt vmcnt(0)"
                     : "=v"(v) : "v"(flags + tid) : "memory");
      } while (__ballot(v < gen) != 0ull);
    }
    __syncthreads();  // #3 — release
  }

  // ---- final linear + sigmoid: out[64][128], block b = blk, thread o = tid
  if (tid < OUT_) {
    const int o = tid;
    const u16* hA = ys0 + (size_t)(T_ - 1) * (B_ * H_) + (size_t)blk * H_;
    const u16* hB = h1b + (size_t)blk * H_;  // t=511 odd -> h1b
    const float* wr = Wlin + (size_t)o * (2 * H_);
    float acc = blin[o];
#pragma unroll 4
    for (int k = 0; k < H_; k += 8) {
      s16x8 h = *(const s16x8*)(hA + k);
      float4 w0 = *(const float4*)(wr + k);
      float4 w1 = *(const float4*)(wr + k + 4);
      acc += bf2f((u16)h[0]) * w0.x + bf2f((u16)h[1]) * w0.y +
             bf2f((u16)h[2]) * w0.z + bf2f((u16)h[3]) * w0.w +
             bf2f((u16)h[4]) * w1.x + bf2f((u16)h[5]) * w1.y +
             bf2f((u16)h[6]) * w1.z + bf2f((u16)h[7]) * w1.w;
    }
#pragma unroll 4
    for (int k = 0; k < H_; k += 8) {
      s16x8 h = load_coh16(hB + k);  // reused address: MALL read
      float4 w0 = *(const float4*)(wr + H_ + k);
      float4 w1 = *(const float4*)(wr + H_ + k + 4);
      acc += bf2f((u16)h[0]) * w0.x + bf2f((u16)h[1]) * w0.y +
             bf2f((u16)h[2]) * w0.z + bf2f((u16)h[3]) * w0.w +
             bf2f((u16)h[4]) * w1.x + bf2f((u16)h[5]) * w1.y +
             bf2f((u16)h[6]) * w1.z + bf2f((u16)h[7]) * w1.w;
    }
    out[blk * OUT_ + o] = 1.0f / (1.0f + expf(-acc));
  }
}

// ---------------------------------------------------------------------------
extern "C" void kernel_launch(void* const* d_in, const int* in_sizes, int n_in,
                              void* d_out, int out_size, void* d_ws, size_t ws_size,
                              hipStream_t stream) {
  const float* x    = (const float*)d_in[0];
  const float* Wih0 = (const float*)d_in[1];
  const float* Whh0 = (const float*)d_in[2];
  const float* bih0 = (const float*)d_in[3];
  const float* bhh0 = (const float*)d_in[4];
  const float* Wih1 = (const float*)d_in[5];
  const float* Whh1 = (const float*)d_in[6];
  const float* bih1 = (const float*)d_in[7];
  const float* bhh1 = (const float*)d_in[8];
  const float* Wlin = (const float*)d_in[9];
  const float* blin = (const float*)d_in[10];
  float* out = (float*)d_out;

  char* ws = (char*)d_ws;
  const size_t TBH = (size_t)T_ * B_ * H_;
  u16* xw0bf = (u16*)ws;                    // 64 MB
  u16* ys0   = (u16*)(ws + TBH * 2);        // 64 MB
  u16* xbf  = ys0;                          // aliases (dead before rnn_seq)
  u16* w0bf = ys0 + (size_t)T_ * B_ * IN_;
  u16* h1a  = (u16*)(ws + 2 * TBH * 2);
  u16* h1b  = h1a + B_ * H_;
  unsigned* flags = (unsigned*)(h1b + B_ * H_);

  hipMemsetAsync(flags, 0, 1024, stream);

  cvt_x<<<8192, 256, 0, stream>>>(x, xbf);
  cvt_w<<<256, 256, 0, stream>>>(Wih0, w0bf);
  xw0_mfma<<<dim3(16, 512), 256, 0, stream>>>(xbf, w0bf, bih0, bhh0, xw0bf);

  const int dyn_lds = 102400;  // 32KB W0 + 64KB W1 + 4KB P
  hipFuncSetAttribute((const void*)rnn_seq, hipFuncAttributeMaxDynamicSharedMemorySize,
                      dyn_lds);
  void* args[] = {&Whh0, &Wih1, &Whh1, &bih1, &bhh1, &Wlin, &blin,
                  &xw0bf, &ys0, &h1a, &h1b, &flags, &out};
  hipLaunchCooperativeKernel((const void*)rnn_seq, dim3(NBLK), dim3(NTHR), args, dyn_lds,
                             stream);
}

// Round 9
// 5874.961 us; speedup vs baseline: 1.4364x; 1.0936x over previous
//
#include <hip/hip_runtime.h>

// Problem constants: B=64, T=512, IN=256, H=1024, L=2, OUT=128
#define B_ 64
#define T_ 512
#define IN_ 256
#define H_ 1024
#define OUT_ 128
#define NBLK 64
#define NTHR 512

typedef __attribute__((ext_vector_type(4))) float f32x4;
typedef __attribute__((ext_vector_type(8))) short s16x8;
typedef __attribute__((ext_vector_type(4))) short s16x4;
typedef unsigned short u16;

#define MFMA16 __builtin_amdgcn_mfma_f32_16x16x32_bf16

union FragU { s16x8 v; unsigned d[4]; };
union Frag4U { s16x4 v; unsigned d[2]; };

// fp32 -> bf16 RNE
__device__ __forceinline__ u16 f2bf(float f) {
  union { float f; unsigned u; } v; v.f = f;
  unsigned r = v.u + 0x7fffu + ((v.u >> 16) & 1u);
  return (u16)(r >> 16);
}
__device__ __forceinline__ float bf2f(u16 h) {
  union { unsigned u; float f; } v; v.u = ((unsigned)h) << 16;
  return v.f;
}
__device__ __forceinline__ s16x8 cvt8(const float* __restrict__ p) {
  float4 a = *(const float4*)p;
  float4 b = *(const float4*)(p + 4);
  s16x8 r;
  r[0] = (short)f2bf(a.x); r[1] = (short)f2bf(a.y);
  r[2] = (short)f2bf(a.z); r[3] = (short)f2bf(a.w);
  r[4] = (short)f2bf(b.x); r[5] = (short)f2bf(b.y);
  r[6] = (short)f2bf(b.z); r[7] = (short)f2bf(b.w);
  return r;
}

// tanh via hardware exp (validated rounds 5/6). Output strictly in [-1,1]
// -> bf16 bit14 is ALWAYS 0 (|x| < 2), which the poison detector relies on.
__device__ __forceinline__ float fast_tanh(float x) {
  float e = __expf(2.0f * x);
  return 1.0f - 2.0f * __builtin_amdgcn_rcpf(e + 1.0f);
}

// Write-through 2B store to MALL (validated rounds 4-6).
__device__ __forceinline__ void store_wt_u16(u16* p, u16 v) {
  unsigned d = v;
  asm volatile("global_store_short %0, %1, off sc0 sc1" :: "v"(p), "v"(d) : "memory");
}

// ---------------------------------------------------------------------------
// prologue kernels (validated rounds 3-6, unchanged)
// ---------------------------------------------------------------------------
__global__ __launch_bounds__(256) void cvt_x(const float* __restrict__ x,
                                             u16* __restrict__ xbf) {
  int i4 = blockIdx.x * 256 + threadIdx.x;
  int r = i4 >> 6;
  int kc = (i4 & 63) * 4;
  int t = r >> 6, b = r & 63;
  float4 v = *(const float4*)(x + ((size_t)b * T_ + t) * IN_ + kc);
  s16x4 o;
  o[0] = (short)f2bf(v.x); o[1] = (short)f2bf(v.y);
  o[2] = (short)f2bf(v.z); o[3] = (short)f2bf(v.w);
  *(s16x4*)(xbf + (size_t)r * IN_ + kc) = o;
}

__global__ __launch_bounds__(256) void cvt_w(const float* __restrict__ w,
                                             u16* __restrict__ wbf) {
  int i = blockIdx.x * 256 + threadIdx.x;
  float4 v = *(const float4*)(w + (size_t)i * 4);
  s16x4 o;
  o[0] = (short)f2bf(v.x); o[1] = (short)f2bf(v.y);
  o[2] = (short)f2bf(v.z); o[3] = (short)f2bf(v.w);
  *(s16x4*)(wbf + (size_t)i * 4) = o;
}

__global__ __launch_bounds__(256) void xw0_mfma(const u16* __restrict__ xbf,
                                                const u16* __restrict__ w0bf,
                                                const float* __restrict__ bih,
                                                const float* __restrict__ bhh,
                                                u16* __restrict__ xw0) {
  __shared__ char ldsW[64 * 512];
  const int tid = threadIdx.x;
  const int j0 = blockIdx.x * 64;
  const int r0 = blockIdx.y * 64;

  for (int c = tid; c < 64 * 32; c += 256) {
    int r = c >> 5, kc = c & 31;
    s16x8 w = *(const s16x8*)(w0bf + (size_t)(j0 + r) * IN_ + kc * 8);
    *(s16x8*)(ldsW + r * 512 + ((kc * 16) ^ ((r & 7) << 4))) = w;
  }
  __syncthreads();

  const int wv = tid >> 6, lane = tid & 63;
  const int col = lane & 15, kg = lane >> 4;
  const int rr = r0 + wv * 16 + col;
  const u16* aRow = xbf + (size_t)rr * IN_ + kg * 8;

  f32x4 acc[4] = {};
#pragma unroll
  for (int k0 = 0; k0 < IN_; k0 += 32) {
    s16x8 a = *(const s16x8*)(aRow + k0);
#pragma unroll
    for (int n = 0; n < 4; ++n) {
      int jr = n * 16 + col;
      s16x8 b = *(const s16x8*)(ldsW + jr * 512 + ((((k0 + kg * 8) << 1)) ^ ((jr & 7) << 4)));
      acc[n] = MFMA16(a, b, acc[n], 0, 0, 0);
    }
  }
#pragma unroll
  for (int n = 0; n < 4; ++n) {
    int j = j0 + n * 16 + col;
    float bs = bih[j] + bhh[j];
#pragma unroll
    for (int q = 0; q < 4; ++q) {
      int r = r0 + wv * 16 + kg * 4 + q;
      xw0[(size_t)r * H_ + j] = f2bf(acc[n][q] + bs);
    }
  }
}

// ---------------------------------------------------------------------------
// Persistent cooperative kernel, R6 topology + DATA-POLL protocol.
// 64 blocks x 512 threads. Block jg owns 16 j-cols; waves 0-3 = layer 0
// (b-tile wv*16), waves 4-7 = layer 1 (b-tile (wv-4)*16), pipelined 1 step.
// ys0 is full T x B x H (fresh address per step) and pre-poisoned to 0xFFFF:
// consumers poll the operand words themselves (bit14 set <=> unwritten,
// since tanh outputs in [-1,1] never set bf16 bit14). No ys flags, no grid
// barrier. h1 uses a 4-deep rotation + per-(bt,blk) flags (off critical path).
// P_ih handoff via parity-double-buffered LDS + one s_barrier per step.
// ---------------------------------------------------------------------------
__global__ __launch_bounds__(NTHR, 1) void rnn_seq(
    const float* __restrict__ Whh0, const float* __restrict__ Wih1,
    const float* __restrict__ Whh1, const float* __restrict__ bih1,
    const float* __restrict__ bhh1, const float* __restrict__ Wlin,
    const float* __restrict__ blin, const u16* __restrict__ xw0bf,
    u16* __restrict__ ys0, u16* __restrict__ h1rot,
    unsigned* __restrict__ h1flag, float* __restrict__ out) {
  extern __shared__ char lds[];
  char* ldsW0 = lds;                    // 16 x 2048 B  (32 KB)
  char* ldsW1 = lds + 32768;            // 16 x 4096 B  (64 KB)
  float* ldsP = (float*)(lds + 98304);  // [2 parity][4 bt][16][16] f32 (8 KB)

  const int tid = threadIdx.x;
  const int blk = blockIdx.x;  // jg 0..63
  const int j0 = blk * 16;
  const int wv = tid >> 6, lane = tid & 63;
  const int col = lane & 15, kg = lane >> 4;
  const int sw = (col & 7) << 4;
  const int bt = wv & 3;
  const int b0 = bt * 16;
  const bool isL1 = wv >= 4;
  const int jt = j0 + col;

  // stage W0 slice (16 x 1024 bf16), fp32->bf16, swizzled (R6-proven)
  for (int c = tid; c < 16 * 128; c += NTHR) {
    int r = c >> 7, kc = c & 127;
    s16x8 w = cvt8(Whh0 + (size_t)(j0 + r) * H_ + kc * 8);
    *(s16x8*)(ldsW0 + r * 2048 + ((kc * 16) ^ ((r & 7) << 4))) = w;
  }
  // stage W1 slice (16 x 2048 bf16): [0,1024)=Wih1, [1024,2048)=Whh1
  for (int c = tid; c < 16 * 256; c += NTHR) {
    int r = c >> 8, kc = c & 255;
    const float* src = (kc < 128) ? (Wih1 + (size_t)(j0 + r) * H_ + kc * 8)
                                  : (Whh1 + (size_t)(j0 + r) * H_ + (kc - 128) * 8);
    *(s16x8*)(ldsW1 + r * 4096 + ((kc * 16) ^ ((r & 7) << 4))) = cvt8(src);
  }
  __syncthreads();

  const float bias1 = bih1[jt] + bhh1[jt];

  for (int s = 0; s <= T_; ++s) {
    if (!isL1) {
      // ---------------- layer-0 waves: ys[s] + P_ih partial ----------------
      u16 xv0 = 0, xv1 = 0, xv2 = 0, xv3 = 0;
      if (s < T_) {
        const u16* xwp =
            xw0bf + ((size_t)s * B_ + b0 + kg * 4) * H_ + jt;
        xv0 = xwp[0]; xv1 = xwp[H_]; xv2 = xwp[2 * H_]; xv3 = xwp[3 * H_];
      }
      f32x4 accY0 = {}, accY1 = {}, accP0 = {}, accP1 = {};
      if (s > 0) {
        const u16* aRow =
            ys0 + ((size_t)(s - 1) * B_ + b0 + col) * H_ + kg * 8;
        FragU af[32];
        unsigned poi;
        do {  // DATA-POLL: reload burst until no word carries poison bit14
#pragma unroll
          for (int i = 0; i < 32; ++i)
            asm volatile("global_load_dwordx4 %0, %1, off sc0 sc1"
                         : "=v"(af[i].v) : "v"(aRow + i * 32) : "memory");
          asm volatile("s_waitcnt vmcnt(0)" ::: "memory");
          __builtin_amdgcn_sched_barrier(0);
          poi = 0u;
#pragma unroll
          for (int i = 0; i < 32; ++i)
            poi |= af[i].d[0] | af[i].d[1] | af[i].d[2] | af[i].d[3];
        } while (__ballot((poi & 0x40004000u) != 0u) != 0ull);
        __builtin_amdgcn_sched_barrier(0);
        const char* w0B = ldsW0 + col * 2048;
        const char* w1B = ldsW1 + col * 4096;
#pragma unroll
        for (int i = 0; i < 32; i += 2) {
          const int kb0 = ((i * 32 + kg * 8) << 1);
          const int kb1 = (((i + 1) * 32 + kg * 8) << 1);
          accY0 = MFMA16(af[i].v, *(const s16x8*)(w0B + (kb0 ^ sw)), accY0, 0, 0, 0);
          accP0 = MFMA16(af[i].v, *(const s16x8*)(w1B + (kb0 ^ sw)), accP0, 0, 0, 0);
          accY1 = MFMA16(af[i + 1].v, *(const s16x8*)(w0B + (kb1 ^ sw)), accY1, 0, 0, 0);
          accP1 = MFMA16(af[i + 1].v, *(const s16x8*)(w1B + (kb1 ^ sw)), accP1, 0, 0, 0);
        }
      }
      if (s < T_) {
        f32x4 aY = accY0 + accY1;
        u16* ysC = ys0 + ((size_t)s * B_ + b0 + kg * 4) * H_ + jt;
        store_wt_u16(ysC + 0 * H_, f2bf(fast_tanh(aY[0] + bf2f(xv0))));
        store_wt_u16(ysC + 1 * H_, f2bf(fast_tanh(aY[1] + bf2f(xv1))));
        store_wt_u16(ysC + 2 * H_, f2bf(fast_tanh(aY[2] + bf2f(xv2))));
        store_wt_u16(ysC + 3 * H_, f2bf(fast_tanh(aY[3] + bf2f(xv3))));
        // no drain needed: consumers poll the data words themselves
      }
      if (s > 0) {  // hand P_ih to layer-1 waves (parity double-buffer)
        f32x4 aP = accP0 + accP1;
        float* pT = ldsP + (s & 1) * 1024 + bt * 256 + (kg * 4) * 16 + col;
        pT[0] = aP[0]; pT[16] = aP[1]; pT[32] = aP[2]; pT[48] = aP[3];
      }
    } else {
      // ---------------- layer-1 waves: h-part (pre-barrier) ----------------
      if (s >= 2) {
        const int t1 = s - 1;
        unsigned fv;
        do {  // h1[t1-1] complete across all 64 blocks (this bt tile)
          asm volatile("global_load_dword %0, %1, off sc0 sc1\n\ts_waitcnt vmcnt(0)"
                       : "=v"(fv) : "v"(h1flag + bt * 64 + lane) : "memory");
        } while (__ballot(fv < (unsigned)t1) != 0ull);
        __builtin_amdgcn_sched_barrier(0);
        const u16* hRow = h1rot + (size_t)((t1 - 1) & 3) * (B_ * H_) +
                          (size_t)(b0 + col) * H_ + kg * 8;
        s16x8 hf[32];
#pragma unroll
        for (int i = 0; i < 32; ++i)
          asm volatile("global_load_dwordx4 %0, %1, off sc0 sc1"
                       : "=v"(hf[i]) : "v"(hRow + i * 32) : "memory");
        asm volatile("s_waitcnt vmcnt(0)" ::: "memory");
        __builtin_amdgcn_sched_barrier(0);
        f32x4 accH0 = {}, accH1 = {};
        const char* w1B = ldsW1 + col * 4096;
#pragma unroll
        for (int i = 0; i < 32; i += 2) {
          const int kb0 = 2048 + ((i * 32 + kg * 8) << 1);
          const int kb1 = 2048 + (((i + 1) * 32 + kg * 8) << 1);
          accH0 = MFMA16(hf[i], *(const s16x8*)(w1B + (kb0 ^ sw)), accH0, 0, 0, 0);
          accH1 = MFMA16(hf[i + 1], *(const s16x8*)(w1B + (kb1 ^ sw)), accH1, 0, 0, 0);
        }
        // stash in accP names for post-barrier use
        f32x4 aH = accH0 + accH1;
        // reuse LDS? no — keep in registers via the names below
        // (fall through with aH in scope)
        // post-barrier section below re-derives via variables:
        // store into per-thread temps:
        // (handled by keeping aH in the outer scope)
        // -- implemented by writing to h1 AFTER the barrier:
        // carry aH through the barrier:
        asm volatile("s_waitcnt lgkmcnt(0)" ::: "memory");
        __builtin_amdgcn_s_barrier();
        const float* pT = ldsP + (s & 1) * 1024 + bt * 256 + (kg * 4) * 16 + col;
        u16* hc = h1rot + (size_t)(t1 & 3) * (B_ * H_) +
                  (size_t)(b0 + kg * 4) * H_ + jt;
        store_wt_u16(hc + 0 * H_, f2bf(fast_tanh(aH[0] + pT[0] + bias1)));
        store_wt_u16(hc + 1 * H_, f2bf(fast_tanh(aH[1] + pT[16] + bias1)));
        store_wt_u16(hc + 2 * H_, f2bf(fast_tanh(aH[2] + pT[32] + bias1)));
        store_wt_u16(hc + 3 * H_, f2bf(fast_tanh(aH[3] + pT[48] + bias1)));
        asm volatile("s_waitcnt vmcnt(0)" ::: "memory");
        if (lane == 0) {
          unsigned g = (unsigned)(t1 + 1);
          asm volatile("global_store_dword %0, %1, off sc0 sc1"
                       :: "v"(h1flag + bt * 64 + blk), "v"(g) : "memory");
        }
        continue;  // barrier already executed this iteration
      } else if (s == 1) {
        // t1 = 0: no h-part; P-only after barrier
        asm volatile("s_waitcnt lgkmcnt(0)" ::: "memory");
        __builtin_amdgcn_s_barrier();
        const float* pT = ldsP + (s & 1) * 1024 + bt * 256 + (kg * 4) * 16 + col;
        u16* hc = h1rot + (size_t)(b0 + kg * 4) * H_ + jt;  // slot 0
        store_wt_u16(hc + 0 * H_, f2bf(fast_tanh(pT[0] + bias1)));
        store_wt_u16(hc + 1 * H_, f2bf(fast_tanh(pT[16] + bias1)));
        store_wt_u16(hc + 2 * H_, f2bf(fast_tanh(pT[32] + bias1)));
        store_wt_u16(hc + 3 * H_, f2bf(fast_tanh(pT[48] + bias1)));
        asm volatile("s_waitcnt vmcnt(0)" ::: "memory");
        if (lane == 0) {
          asm volatile("global_store_dword %0, %1, off sc0 sc1"
                       :: "v"(h1flag + bt * 64 + blk), "v"(1u) : "memory");
        }
        continue;
      }
    }
    asm volatile("s_waitcnt lgkmcnt(0)" ::: "memory");
    __builtin_amdgcn_s_barrier();
  }

  // ---------------- finale: out[64][128], block owns batch row blk ---------
  const int bt2 = blk >> 4;
  if (wv == 0) {  // confirm h1[511] for tile bt2 across all blocks
    unsigned fv;
    do {
      asm volatile("global_load_dword %0, %1, off sc0 sc1\n\ts_waitcnt vmcnt(0)"
                   : "=v"(fv) : "v"(h1flag + bt2 * 64 + lane) : "memory");
    } while (__ballot(fv < (unsigned)T_) != 0ull);
  }
  asm volatile("s_waitcnt vmcnt(0) lgkmcnt(0)" ::: "memory");
  __builtin_amdgcn_s_barrier();

  u16* rowbuf = (u16*)ldsP;  // 4 KB: [0,1024)=ys row, [1024,2048)=h1 row
  {
    if (tid < 256) {  // ys[511] row blk, with data-poll
      const u16* p = ys0 + ((size_t)(T_ - 1) * B_ + blk) * H_ + tid * 4;
      Frag4U q;
      do {
        asm volatile("global_load_dwordx2 %0, %1, off sc0 sc1\n\ts_waitcnt vmcnt(0)"
                     : "=v"(q.v) : "v"(p) : "memory");
      } while (__ballot(((q.d[0] | q.d[1]) & 0x40004000u) != 0u) != 0ull);
      *(s16x4*)(rowbuf + tid * 4) = q.v;
    } else {  // h1[511] row blk (slot 3), flag-gated
      const u16* p = h1rot + (size_t)3 * (B_ * H_) + (size_t)blk * H_ + (tid - 256) * 4;
      Frag4U q;
      asm volatile("global_load_dwordx2 %0, %1, off sc0 sc1\n\ts_waitcnt vmcnt(0)"
                   : "=v"(q.v) : "v"(p) : "memory");
      *(s16x4*)(rowbuf + 1024 + (tid - 256) * 4) = q.v;
    }
  }
  asm volatile("s_waitcnt lgkmcnt(0)" ::: "memory");
  __builtin_amdgcn_s_barrier();

  if (tid < OUT_) {
    const int o = tid;
    const float* wr = Wlin + (size_t)o * (2 * H_);
    float acc = blin[o];
#pragma unroll 4
    for (int k = 0; k < 2 * H_; k += 8) {
      s16x8 h = *(const s16x8*)(rowbuf + k);
      float4 w0 = *(const float4*)(wr + k);
      float4 w1 = *(const float4*)(wr + k + 4);
      acc += bf2f((u16)h[0]) * w0.x + bf2f((u16)h[1]) * w0.y +
             bf2f((u16)h[2]) * w0.z + bf2f((u16)h[3]) * w0.w +
             bf2f((u16)h[4]) * w1.x + bf2f((u16)h[5]) * w1.y +
             bf2f((u16)h[6]) * w1.z + bf2f((u16)h[7]) * w1.w;
    }
    out[blk * OUT_ + o] = 1.0f / (1.0f + expf(-acc));
  }
}

// ---------------------------------------------------------------------------
extern "C" void kernel_launch(void* const* d_in, const int* in_sizes, int n_in,
                              void* d_out, int out_size, void* d_ws, size_t ws_size,
                              hipStream_t stream) {
  const float* x    = (const float*)d_in[0];
  const float* Wih0 = (const float*)d_in[1];
  const float* Whh0 = (const float*)d_in[2];
  const float* bih0 = (const float*)d_in[3];
  const float* bhh0 = (const float*)d_in[4];
  const float* Wih1 = (const float*)d_in[5];
  const float* Whh1 = (const float*)d_in[6];
  const float* bih1 = (const float*)d_in[7];
  const float* bhh1 = (const float*)d_in[8];
  const float* Wlin = (const float*)d_in[9];
  const float* blin = (const float*)d_in[10];
  float* out = (float*)d_out;

  char* ws = (char*)d_ws;
  const size_t TBH = (size_t)T_ * B_ * H_;
  u16* xw0bf = (u16*)ws;                        // 64 MiB
  u16* ys0   = (u16*)(ws + (64ull << 20));      // 64 MiB (poisoned per launch)
  u16* xbf   = ys0;                             // prologue-only aliases
  u16* w0bf  = ys0 + (size_t)T_ * B_ * IN_;     //  (dead before poisoning)
  u16* h1rot = (u16*)(ws + (128ull << 20));     // 4 x 128 KiB rotation
  unsigned* h1flag = (unsigned*)(ws + (128ull << 20) + (512u << 10));  // 1 KiB

  hipMemsetAsync(h1flag, 0, 1024, stream);

  cvt_x<<<8192, 256, 0, stream>>>(x, xbf);
  cvt_w<<<256, 256, 0, stream>>>(Wih0, w0bf);
  xw0_mfma<<<dim3(16, 512), 256, 0, stream>>>(xbf, w0bf, bih0, bhh0, xw0bf);

  // poison ys0 AFTER xw0_mfma consumed the aliased xbf/w0bf (stream-ordered)
  hipMemsetAsync(ys0, 0xFF, TBH * 2, stream);

  const int dyn_lds = 106496;  // 32K W0 + 64K W1 + 8K P/rowbuf
  hipFuncSetAttribute((const void*)rnn_seq, hipFuncAttributeMaxDynamicSharedMemorySize,
                      dyn_lds);
  void* args[] = {&Whh0, &Wih1, &Whh1, &bih1, &bhh1, &Wlin,
                  &blin, &xw0bf, &ys0, &h1rot, &h1flag, &out};
  hipLaunchCooperativeKernel((const void*)rnn_seq, dim3(NBLK), dim3(NTHR), args, dyn_lds,
                             stream);
}